// Round 7
// baseline (969.018 us; speedup 1.0000x reference)
//
#include <hip/hip_runtime.h>
#include <cmath>

#define NS 64
#define NN 128
#define NT 1000
#define CH 8                                // steps per obuf half-buffer
#define ROWDW (NN * 3 + 8)                  // 392 dwords per buffered step-row
#define WROWS 130                           // 128 rows of w + 2 zero rows
#define WL_DW (WROWS * NN)                  // 16640
#define OBUF_DW (2 * CH * ROWDW)            // 6272 (double-buffered)
#define NRING_DW (16 * 256)                 // 16 slots x 1KB noise rows
#define ERING_DW (16 * 128)                 // 16 slots x 512B exp rows
#define LDS_BYTES ((WL_DW + OBUF_DW + NRING_DW + ERING_DW) * 4)   // 116224

// == npy_logaddexpf(x, 0), branch-free but bit-identical:
//   x>0: fmax=x, |x|=x  -> x + log1p(exp(-x)) ; x<0: 0 + log1p(exp(x)) ; x==0 -> LOGE2
__device__ __forceinline__ float softplus_np(float x) {
    float r = fmaxf(x, 0.0f) + log1pf(expf(-fabsf(x)));
    return (x == 0.0f) ? 0.693147180559945309f : r;
}

// Barrier WITHOUT the compiler's vmcnt(0) drain: LDS-visibility only.
__device__ __forceinline__ void sync_lds() {
    __builtin_amdgcn_sched_barrier(0);
    asm volatile("s_waitcnt lgkmcnt(0)" ::: "memory");
    __builtin_amdgcn_s_barrier();
    __builtin_amdgcn_sched_barrier(0);
}

// async global->LDS, 16B/lane; LDS dest = wave-uniform base + lane*16 (m104)
__device__ __forceinline__ void g2l16(const float* g, float* l) {
    __builtin_amdgcn_global_load_lds(
        (const __attribute__((address_space(1))) void*)g,
        (__attribute__((address_space(3))) void*)l,
        16, 0, 0);
}

__global__ __launch_bounds__(128) void snn_scan_kernel(
    const float* __restrict__ w,
    const float* __restrict__ ic,
    const float* __restrict__ v0,
    const float* __restrict__ i0,
    const float* __restrict__ s0,
    const float* __restrict__ mu,
    const float* __restrict__ sigma,
    const float* __restrict__ noise,      // [T, S, N, 2]
    const float* __restrict__ exp_draws,  // [T, S, N]
    float* __restrict__ out)              // [S, N, T, 3]
{
    #pragma clang fp contract(off)
    extern __shared__ float smem[];
    float* wl    = smem;                  // [130][128]: w rows + 2 zero rows
    float* obuf  = smem + WL_DW;          // [2][CH][ROWDW] output staging
    float* nring = smem + WL_DW + OBUF_DW;             // [16][256] noise rows
    float* ering = smem + WL_DW + OBUF_DW + NRING_DW;  // [16][128] exp rows

    const int samp = blockIdx.x;
    const int tid  = threadIdx.x;
    const int wid  = tid >> 6;            // wave 0 = compute, wave 1 = flush
    const int l    = tid & 63;

    {   // cooperative stage of w (4096 float4 / 128 threads) + zero rows
        const float4* src = (const float4*)w;
        float4* dst = (float4*)wl;
        #pragma unroll
        for (int it = 0; it < 32; ++it)
            dst[it * 128 + tid] = src[it * 128 + tid];
        ((float2*)(wl + 128 * NN))[tid] = make_float2(0.0f, 0.0f);
    }

    const float SQDT  = sqrtf(0.01f);     // 0x3DCCCCCD == np.sqrt(float32(0.01))
    const float DTf   = 0.01f;
    const float LOGE2 = 0.693147180559945309f;

    const float* nrow0 = noise + (size_t)samp * (NN * 2) + 4 * l;      // +t*S*N*2
    const float* erow0 = exp_draws + (size_t)samp * NN + 4 * l;        // +t*S*N
    float* outb = out + (size_t)samp * NN * NT * 3;

    float mu1 = 0.f, negmu2 = 0.f, g00 = 0.f, g01 = 0.f, g10 = 0.f, g11 = 0.f;
    float ic0 = 0.f, ic1 = 0.f;
    float v_0 = 0.f, v_1 = 0.f, i_0 = 0.f, i_1 = 0.f, s_0 = 0.f, s_1 = 0.f;
    float sp_0 = 0.f, sp_1 = 0.f;

    if (wid == 0) {
        __builtin_amdgcn_s_setprio(1);    // compute wave owns the critical path
        mu1 = mu[0]; negmu2 = -mu[1];
        g00 = sigma[0]; g01 = sigma[1]; g10 = sigma[2]; g11 = sigma[3];
        ic0 = ic[2 * l]; ic1 = ic[2 * l + 1];
        v_0 = v0[samp * NN + 2 * l]; v_1 = v0[samp * NN + 2 * l + 1];
        i_0 = i0[samp * NN + 2 * l]; i_1 = i0[samp * NN + 2 * l + 1];
        s_0 = s0[samp * NN + 2 * l]; s_1 = s0[samp * NN + 2 * l + 1];
        sp_0 = softplus_np(v_0); sp_1 = softplus_np(v_1);

        // prologue: 8 slot-pairs in flight (16 vm ops), FIFO order n,e,n,e,...
        #pragma unroll
        for (int t = 0; t < 8; ++t) {
            g2l16(nrow0 + (size_t)t * (NS * NN * 2), nring + t * 256);
            if (l < 32)
                g2l16(erow0 + (size_t)t * (NS * NN), ering + t * 128);
        }
    }
    sync_lds();   // w visible; ring loads stay in flight (lgkm-only barrier)

    const float2* wl2 = (const float2*)wl;

    auto flushBuf = [&](int b, int tb0) {
        // CH steps x 128 neurons; each neuron's run ([CH][3] dwords = 96B)
        // contiguous in global at outb + n*NT*3 + tb0*3
        const float* ob = obuf + b * (CH * ROWDW);
        #pragma unroll
        for (int j = 0; j < 24; ++j) {
            const int f = j * 64 + l;        // float2 slot 0..1535
            const int n = f / 12;            // neuron
            const int r = f - n * 12;        // float2 slot within run
            const int da = 2 * r;
            const float x = ob[((da    ) / 3) * ROWDW + n * 3 + ((da    ) % 3)];
            const float y = ob[((da + 1) / 3) * ROWDW + n * 3 + ((da + 1) % 3)];
            *(float2*)(outb + (size_t)n * (NT * 3) + (size_t)tb0 * 3 + da) =
                make_float2(x, y);
        }
    };

    int cur = 0;
    #pragma clang loop unroll(disable)
    for (int blk = 0; blk < NT / CH; ++blk) {
        if (wid == 0) {
            float* obase = obuf + cur * (CH * ROWDW) + 6 * l;
            // ROLLED per-step loop: keep the hot body small (I$-resident)
            #pragma clang loop unroll(disable)
            for (int k = 0; k < CH; ++k) {
                #pragma clang fp contract(off)
                const int t = blk * CH + k;

                // retire exactly this step's slot pair, then read it
                asm volatile("s_waitcnt vmcnt(14)" ::: "memory");
                __builtin_amdgcn_sched_barrier(0);
                const int cs = t & 15;
                const float4 nz = *(const float4*)(nring + cs * 256 + 4 * l);
                const float2 ed = *(const float2*)(ering + cs * 128 + 2 * l);

                // issue t+8 pair (clamped at tail to keep FIFO invariant)
                const int tp = (t + 8) < NT ? (t + 8) : NT - 1;
                const int ps = (t + 8) & 15;
                g2l16(nrow0 + (size_t)tp * (NS * NN * 2), nring + ps * 256);
                if (l < 32)
                    g2l16(erow0 + (size_t)tp * (NS * NN), ering + ps * 128);

                const float dw00 = nz.x * SQDT, dw01 = nz.y * SQDT;
                const float dw10 = nz.z * SQDT, dw11 = nz.w * SQDT;

                const float nv0 = (dw00 * g00) + (dw01 * g01);
                const float nv1 = (dw10 * g00) + (dw11 * g01);
                const float ni0 = (dw00 * g10) + (dw01 * g11);
                const float ni1 = (dw10 * g10) + (dw11 * g11);

                const float t0 = (i_0 + ic0) - v_0;
                const float t1 = (i_1 + ic1) - v_1;
                const float vt0 = (v_0 + DTf * (mu1 * t0)) + nv0;
                const float vt1 = (v_1 + DTf * (mu1 * t1)) + nv1;
                const float it0 = (i_0 + DTf * (negmu2 * i_0)) + ni0;
                const float it1 = (i_1 + DTf * (negmu2 * i_1)) + ni1;
                s_0 = s_0 + DTf * sp_0;       // sp_* = softplus(carry v)
                s_1 = s_1 + DTf * sp_1;

                const bool k0 = (s_0 >= 0.0f), k1 = (s_1 >= 0.0f);
                unsigned long long me = __ballot(k0);   // bit b -> neuron 2b
                unsigned long long mo = __ballot(k1);   // bit b -> neuron 2b+1

                // speculative next-step softplus overlaps coupling LDS wait
                const float spv0 = softplus_np(vt0);
                const float spv1 = softplus_np(vt1);

                float a0 = 0.0f, a1 = 0.0f;
                if (me | mo) {                // wave-uniform skip of empty steps
                    auto ext1 = [&]() -> int {   // ascending order; empty -> zero-row
                        const int be = me ? (int)__builtin_ctzll(me) : 64;
                        const int bo = mo ? (int)__builtin_ctzll(mo) : 64;
                        const int ce = 2 * be, co = 2 * bo + 1;
                        const bool te = ce < co;
                        const unsigned long long me2 = me & (me - 1);
                        const unsigned long long mo2 = mo & (mo - 1);
                        me = te ? me2 : me;
                        mo = te ? mo : mo2;
                        return te ? ce : co;
                    };
                    const int r1 = ext1();
                    const int r2 = ext1();
                    const float2 q1 = wl2[r1 * 64 + l];   // 2 independent ds_read_b64
                    const float2 q2 = wl2[r2 * 64 + l];
                    a0 = q1.x;  a1 = q1.y;                // ascending-order fp32 sum
                    a0 += q2.x; a1 += q2.y;
                    #pragma clang loop unroll(disable)
                    while (me | mo) {                     // >=3 spikes: uncommon
                        const int r = ext1();
                        const float2 q = wl2[r * 64 + l];
                        a0 += q.x; a1 += q.y;
                    }
                }
                i_0 = it0 + a0;               // unconditional add: bit-identical
                i_1 = it1 + a1;

                v_0 = k0 ? 0.0f : vt0;      v_1 = k1 ? 0.0f : vt1;
                s_0 = k0 ? -ed.x : s_0;     s_1 = k1 ? -ed.y : s_1;
                sp_0 = k0 ? LOGE2 : spv0;   sp_1 = k1 ? LOGE2 : spv1;

                float* row = obase + k * ROWDW;
                *(float2*)(row)     = make_float2(v_0, i_0);
                *(float2*)(row + 2) = make_float2(s_0, v_1);
                *(float2*)(row + 4) = make_float2(i_1, s_1);
            }
        } else if (blk > 0) {
            flushBuf(cur ^ 1, (blk - 1) * CH);
        }
        sync_lds();                       // lgkm-only barrier: vm stays in flight
        cur ^= 1;
    }
    if (wid == 1) flushBuf(cur ^ 1, NT - CH);   // last block

    __builtin_amdgcn_s_setprio(0);
}

extern "C" void kernel_launch(void* const* d_in, const int* in_sizes, int n_in,
                              void* d_out, int out_size, void* d_ws, size_t ws_size,
                              hipStream_t stream) {
    const float* w         = (const float*)d_in[0];
    const float* ic        = (const float*)d_in[1];
    const float* v0        = (const float*)d_in[2];
    const float* i0        = (const float*)d_in[3];
    const float* s0        = (const float*)d_in[4];
    const float* mu        = (const float*)d_in[5];
    const float* sigma     = (const float*)d_in[6];
    const float* noise     = (const float*)d_in[7];
    const float* exp_draws = (const float*)d_in[8];
    float* out = (float*)d_out;

    (void)hipFuncSetAttribute((const void*)snn_scan_kernel,
                              hipFuncAttributeMaxDynamicSharedMemorySize,
                              LDS_BYTES);

    snn_scan_kernel<<<dim3(NS), dim3(128), LDS_BYTES, stream>>>(
        w, ic, v0, i0, s0, mu, sigma, noise, exp_draws, out);
}

// Round 9
// 575.426 us; speedup vs baseline: 1.6840x; 1.6840x over previous
//
#include <hip/hip_runtime.h>
#include <cmath>

#define NS 64
#define NN 128
#define NT 1000
#define CH 8                                // steps per obuf half-buffer
#define WROWS 130                           // 128 rows of w + 2 zero rows
#define WL_DW (WROWS * NN)                  // 16640
#define OBUF_DW (2 * CH * 3 * NN)           // 6144: [2][CH][3][128] dwords
#define LDS_BYTES ((WL_DW + OBUF_DW) * 4 + 32)   // 91168

// == npy_logaddexpf(x, 0), branch-free but bit-identical:
//   x>0: fmax=x, |x|=x  -> x + log1p(exp(-x)) ; x<0: 0 + log1p(exp(x)) ; x==0 -> LOGE2
__device__ __forceinline__ float softplus_np(float x) {
    float r = fmaxf(x, 0.0f) + log1pf(expf(-fabsf(x)));
    return (x == 0.0f) ? 0.693147180559945309f : r;
}

// Barrier WITHOUT the compiler's vmcnt(0) drain: LDS-visibility only.
__device__ __forceinline__ void sync_lds() {
    __builtin_amdgcn_sched_barrier(0);
    asm volatile("s_waitcnt lgkmcnt(0)" ::: "memory");
    __builtin_amdgcn_s_barrier();
    __builtin_amdgcn_sched_barrier(0);
}

__global__ __launch_bounds__(192) void snn_scan_kernel(
    const float* __restrict__ w,
    const float* __restrict__ ic,
    const float* __restrict__ v0,
    const float* __restrict__ i0,
    const float* __restrict__ s0,
    const float* __restrict__ mu,
    const float* __restrict__ sigma,
    const float* __restrict__ noise,      // [T, S, N, 2]
    const float* __restrict__ exp_draws,  // [T, S, N]
    float* __restrict__ out)              // [S, N, T, 3]
{
    #pragma clang fp contract(off)
    extern __shared__ float smem[];
    float* wl   = smem;                   // [130][128]: w rows + 2 zero rows
    float* obuf = smem + WL_DW;           // [2][CH][3][128] output staging
    unsigned long long* mslot =           // [2 parity][2 waves] spike masks
        (unsigned long long*)(smem + WL_DW + OBUF_DW);

    const int samp = blockIdx.x;
    const int tid  = threadIdx.x;
    const int wid  = tid >> 6;            // waves 0,1 = compute; wave 2 = flush
    const int l    = tid & 63;
    const int n    = (wid << 6) | l;      // neuron (waves 0,1): 1 neuron/lane

    if (tid < 128) {                      // stage w + zero rows (one-time)
        const float4* src = (const float4*)w;
        float4* dst = (float4*)wl;
        #pragma unroll
        for (int it = 0; it < 32; ++it)
            dst[it * 128 + tid] = src[it * 128 + tid];
        ((float2*)(wl + NN * NN))[tid] = make_float2(0.0f, 0.0f);
    }

    const float SQDT  = sqrtf(0.01f);     // 0x3DCCCCCD == np.sqrt(float32(0.01))
    const float DTf   = 0.01f;
    const float LOGE2 = 0.693147180559945309f;

    float* outb = out + (size_t)samp * NN * NT * 3;

    float mu1 = 0.f, negmu2 = 0.f, g00 = 0.f, g01 = 0.f, g10 = 0.f, g11 = 0.f;
    float icn = 0.f, v_ = 0.f, i_ = 0.f, s_ = 0.f, sp = 0.f;
    float2 nb0 = {}, nb1 = {}, nb2 = {}, nb3 = {}, nb4 = {}, nb5 = {}, nb6 = {}, nb7 = {};
    float  eb0 = 0, eb1 = 0, eb2 = 0, eb3 = 0, eb4 = 0, eb5 = 0, eb6 = 0, eb7 = 0;

    const float* nzb = noise + (size_t)samp * (NN * 2) + n * 2;   // + t*NS*NN*2
    const float* edb = exp_draws + (size_t)samp * NN + n;         // + t*NS*NN

    if (wid < 2) {
        __builtin_amdgcn_s_setprio(1);    // compute waves own the critical path
        mu1 = mu[0]; negmu2 = -mu[1];
        g00 = sigma[0]; g01 = sigma[1]; g10 = sigma[2]; g11 = sigma[3];
        icn = ic[n];
        v_ = v0[samp * NN + n];
        i_ = i0[samp * NN + n];
        s_ = s0[samp * NN + n];
        sp = softplus_np(v_);
        nb0 = *(const float2*)(nzb + 0ull * (NS * NN * 2)); eb0 = edb[0ull * (NS * NN)];
        nb1 = *(const float2*)(nzb + 1ull * (NS * NN * 2)); eb1 = edb[1ull * (NS * NN)];
        nb2 = *(const float2*)(nzb + 2ull * (NS * NN * 2)); eb2 = edb[2ull * (NS * NN)];
        nb3 = *(const float2*)(nzb + 3ull * (NS * NN * 2)); eb3 = edb[3ull * (NS * NN)];
        nb4 = *(const float2*)(nzb + 4ull * (NS * NN * 2)); eb4 = edb[4ull * (NS * NN)];
        nb5 = *(const float2*)(nzb + 5ull * (NS * NN * 2)); eb5 = edb[5ull * (NS * NN)];
        nb6 = *(const float2*)(nzb + 6ull * (NS * NN * 2)); eb6 = edb[6ull * (NS * NN)];
        nb7 = *(const float2*)(nzb + 7ull * (NS * NN * 2)); eb7 = edb[7ull * (NS * NN)];
    }
    sync_lds();                           // w + zero rows visible

    if (wid < 2) {
        // ---------------- compute waves ----------------
        int cur = 0;
        float* ob = obuf + n;             // + (cur*CH*3 + k*3 + c)*NN

        auto STEP = [&](int k, int blk, float2& nb, float& eb) {
            #pragma clang fp contract(off)
            const int t = blk * CH + k;
            // --- pre-barrier: s-chain + spike-mask publish (depends on s,sp only)
            s_ = s_ + DTf * sp;
            const bool kk = (s_ >= 0.0f);
            const unsigned long long mym = __ballot(kk);
            if (l == 0) mslot[(k & 1) * 2 + wid] = mym;
            sync_lds();
            // --- post-barrier: drift + noise overlap the mask-read latency
            const float2 nz = nb;
            const float  ed = eb;
            const int tp = (t + 8) < NT ? (t + 8) : NT - 1;   // clamped prefetch
            nb = *(const float2*)(nzb + (size_t)tp * (NS * NN * 2));
            eb = edb[(size_t)tp * (NS * NN)];

            const float dw0 = nz.x * SQDT, dw1 = nz.y * SQDT;
            const float nv = (dw0 * g00) + (dw1 * g01);
            const float ni = (dw0 * g10) + (dw1 * g11);
            const float tt = (i_ + icn) - v_;
            const float vt = (v_ + DTf * (mu1 * tt)) + nv;
            const float it = (i_ + DTf * (negmu2 * i_)) + ni;
            const float spv = softplus_np(vt);   // speculative next-step intensity

            unsigned long long m0 = mslot[(k & 1) * 2 + 0];   // neurons 0..63
            unsigned long long m1 = mslot[(k & 1) * 2 + 1];   // neurons 64..127

            float a = 0.0f;
            if (m0 | m1) {                // wave-uniform skip of empty steps
                auto ext1 = [&]() -> int {    // ascending order: drain m0 then m1
                    const bool u0 = (m0 != 0);
                    const unsigned long long m = u0 ? m0 : m1;
                    const int b = m ? (int)__builtin_ctzll(m) : 99;
                    const int r = (b == 99) ? 128 : ((u0 ? 0 : 64) + b);
                    const unsigned long long m0n = m0 & (m0 - 1);
                    const unsigned long long m1n = m1 & (m1 - 1);
                    m0 = u0 ? m0n : m0;
                    m1 = u0 ? m1 : m1n;
                    return r;             // empty -> zero row 128 (+0.0 exact)
                };
                const int r1 = ext1(); const int r2 = ext1();
                const int r3 = ext1(); const int r4 = ext1();
                const float q1 = wl[r1 * NN + n];   // 4 independent ds_read_b32
                const float q2 = wl[r2 * NN + n];
                const float q3 = wl[r3 * NN + n];
                const float q4 = wl[r4 * NN + n];
                a = q1;  a += q2;  a += q3;  a += q4;   // ascending fp32 sum
                #pragma clang loop unroll(disable)
                while (m0 | m1) {                     // >=5 spikes: rare
                    const int r = ext1();
                    a += wl[r * NN + n];
                }
            }
            i_ = it + a;                  // unconditional add: bit-identical

            v_ = kk ? 0.0f : vt;
            s_ = kk ? -ed : s_;
            sp = kk ? LOGE2 : spv;

            float* row = ob + (cur * CH * 3 + k * 3) * NN;
            row[0 * NN] = v_;             // [CH][3][128]: 3x ds_write_b32
            row[1 * NN] = i_;
            row[2 * NN] = s_;
        };

        #pragma clang loop unroll(disable)
        for (int blk = 0; blk < NT / CH; ++blk) {
            STEP(0, blk, nb0, eb0);
            STEP(1, blk, nb1, eb1);
            STEP(2, blk, nb2, eb2);
            STEP(3, blk, nb3, eb3);
            STEP(4, blk, nb4, eb4);
            STEP(5, blk, nb5, eb5);
            STEP(6, blk, nb6, eb6);
            STEP(7, blk, nb7, eb7);
            cur ^= 1;
        }
    } else {
        // ---------------- flush wave ----------------
        auto flush3 = [&](int b, int tb0, int kk) {
            // layout [CH][3][128] == [24][128]: neuron nn's 24 dwords are column nn
            const float* ob2 = obuf + b * (CH * 3 * NN);
            #pragma unroll
            for (int j = 3 * kk; j < 3 * kk + 3; ++j) {
                const int f = j * 64 + l;        // float2 slot 0..1535
                const int nn2 = f / 12;          // neuron
                const int da = 2 * (f - nn2 * 12);
                const float x = ob2[(da    ) * NN + nn2];
                const float y = ob2[(da + 1) * NN + nn2];
                *(float2*)(outb + (size_t)nn2 * (NT * 3) + (size_t)tb0 * 3 + da) =
                    make_float2(x, y);
            }
        };
        int cur = 0;
        #pragma clang loop unroll(disable)
        for (int blk = 0; blk < NT / CH; ++blk) {
            #pragma clang loop unroll(disable)
            for (int k = 0; k < CH; ++k) {
                sync_lds();               // match compute waves' per-step barrier
                if (blk > 0) flush3(cur ^ 1, (blk - 1) * CH, k);
            }
            cur ^= 1;
        }
    }

    // FIX (R8 bug): the last CH steps' obuf writes happen AFTER barrier
    // (124,7). All waves must cross one more barrier before the tail flush
    // reads them. Barrier counts stay matched across all three waves.
    sync_lds();

    if (wid == 2) {
        // tail: flush the final half-buffer (steps NT-CH..NT-1, buffer 0)
        const float* ob2 = obuf + 0 * (CH * 3 * NN);   // 125 blks -> cur^1 == 0
        #pragma unroll
        for (int j = 0; j < 24; ++j) {
            const int f = j * 64 + l;
            const int nn2 = f / 12;
            const int da = 2 * (f - nn2 * 12);
            const float x = ob2[(da    ) * NN + nn2];
            const float y = ob2[(da + 1) * NN + nn2];
            *(float2*)(outb + (size_t)nn2 * (NT * 3) + (size_t)(NT - CH) * 3 + da) =
                make_float2(x, y);
        }
    }
}

extern "C" void kernel_launch(void* const* d_in, const int* in_sizes, int n_in,
                              void* d_out, int out_size, void* d_ws, size_t ws_size,
                              hipStream_t stream) {
    const float* w         = (const float*)d_in[0];
    const float* ic        = (const float*)d_in[1];
    const float* v0        = (const float*)d_in[2];
    const float* i0        = (const float*)d_in[3];
    const float* s0        = (const float*)d_in[4];
    const float* mu        = (const float*)d_in[5];
    const float* sigma     = (const float*)d_in[6];
    const float* noise     = (const float*)d_in[7];
    const float* exp_draws = (const float*)d_in[8];
    float* out = (float*)d_out;

    (void)hipFuncSetAttribute((const void*)snn_scan_kernel,
                              hipFuncAttributeMaxDynamicSharedMemorySize,
                              LDS_BYTES);

    snn_scan_kernel<<<dim3(NS), dim3(192), LDS_BYTES, stream>>>(
        w, ic, v0, i0, s0, mu, sigma, noise, exp_draws, out);
}